// Round 7
// baseline (3589.578 us; speedup 1.0000x reference)
//
#include <hip/hip_runtime.h>
#include <stdint.h>

// ---------------- problem constants ----------------
#define TT 512
#define BB 256
#define HH 256
#define II 128
#define OUTD 128
#define EPSV 1e-5f

// ---------------- geometry ----------------
// v8: 32 clusters x 8 rows as before, but each stage WG multiplexes TWO
// clusters (a "pair"): 16 pairs x 4 stages = 64 WGs of 512 thr.
//   M1: gi1 = x@Wih1^T   A: h1 recurrence   M2: gi2 = h1@Wih2^T   B: h2 + BN
// Rationale (v5 counters): period 3.7us/step vs ~1.2us compute = ~2.5us
// exposed MALL round-trip per step; v7 proved sc0-only XCD-L2 rings are NOT
// coherent (absmax 1.17). So keep v5's proven system-scope transport and hide
// the RT under the second cluster's compute: per superstep, c0's ring ops
// overlap c1's MFMA+gates and vice versa. Weights are shared (same 192 VGPR).
// prog counters merged per pair (both clusters advance in lockstep).
// Protocol = v5 verbatim: posts every 2 steps after counted vmcnt proving
// stores(t-1) complete (mapping P=p => ring stores of steps <= p complete);
// polls every 8 (fwd: A>=t+10 on M1, M2>=u+11 on A, B>=v+10 on M2;
// back: >= t-24); RD=32 (max lead 31 < 32). rz preacts packed in ONE u64
// (bf16 pair each), n preacts fp32 u64.
#define NPAIR 16
#define RPC 8
#define RD  32
#define HPAD 264
#define SPIN_CAP (1 << 17)

#define P_M1 0
#define P_A  1
#define P_M2 2
#define P_B  3

// ---------------- workspace layout (bytes), total ~100 MB (v5-proven) -------
#define OFF_PROG     0u
#define OFF_BNSUM    1024u
#define OFF_BNSQ     2048u
#define OFF_ZERO_END 3072u
#define OFF_GI1      65536u
#define GI_SLOT      16384u                        // 16 tiles x (rz u64[64] + n u64[64])
#define GI1_BYTES    ((unsigned)32*RD*GI_SLOT)     // 16 MB
#define OFF_H1R      (OFF_GI1 + GI1_BYTES)
#define H1R_BYTES    ((unsigned)32*RD*4096u)       // 4 MB
#define OFF_GI2      (OFF_H1R + H1R_BYTES)
#define GI2_BYTES    ((unsigned)32*RD*GI_SLOT)     // 16 MB
#define OFF_H2SEQ    (OFF_GI2 + GI2_BYTES)         // 64 MB bf16 [t][b][h]

typedef short bf16x8 __attribute__((ext_vector_type(8)));
typedef float f32x4  __attribute__((ext_vector_type(4)));
typedef unsigned long long u64;

__device__ __forceinline__ short f2bf(float v) {
    unsigned u = __float_as_uint(v);
    u += 0x7fffu + ((u >> 16) & 1u);
    return (short)(u >> 16);
}
__device__ __forceinline__ float bf2f(short s) {
    return __uint_as_float(((unsigned)(unsigned short)s) << 16);
}
__device__ __forceinline__ float bf2f_lo(unsigned u) { return __uint_as_float(u << 16); }
__device__ __forceinline__ float bf2f_hi(unsigned u) { return __uint_as_float(u & 0xffff0000u); }
__device__ __forceinline__ unsigned pk2bf(float a, float b) {
    return (unsigned)(unsigned short)f2bf(a) | ((unsigned)(unsigned short)f2bf(b) << 16);
}
__device__ __forceinline__ bf16x8 ldfrag_f32(const float* __restrict__ p) {
    const float4* q = (const float4*)p;
    float4 a = q[0], b = q[1];
    bf16x8 f;
    f[0]=f2bf(a.x); f[1]=f2bf(a.y); f[2]=f2bf(a.z); f[3]=f2bf(a.w);
    f[4]=f2bf(b.x); f[5]=f2bf(b.y); f[6]=f2bf(b.z); f[7]=f2bf(b.w);
    return f;
}
__device__ __forceinline__ float sigm_f(float x) {
    float e = __expf(-x);
    return __builtin_amdgcn_rcpf(1.f + e);
}
__device__ __forceinline__ float tanh_f(float x) {
    float ax = fabsf(x);
    float e  = __expf(-2.f * ax);
    float t  = (1.f - e) * __builtin_amdgcn_rcpf(1.f + e);
    return copysignf(t, x);
}
__device__ __forceinline__ void poll_ge(const unsigned* p, int tgt) {
    if (tgt <= 0) return;
    int spins = 0;
    while ((int)__hip_atomic_load((unsigned*)p, __ATOMIC_RELAXED, __HIP_MEMORY_SCOPE_SYSTEM) < tgt) {
        __builtin_amdgcn_s_sleep(2);
        if (++spins > SPIN_CAP) break;       // watchdog
    }
    asm volatile("" ::: "memory");
}
__device__ __forceinline__ void poll2_ge(const unsigned* p1, int t1, const unsigned* p2, int t2) {
    int spins = 0;
    for (;;) {
        int a = (int)__hip_atomic_load((unsigned*)p1, __ATOMIC_RELAXED, __HIP_MEMORY_SCOPE_SYSTEM);
        int b = (int)__hip_atomic_load((unsigned*)p2, __ATOMIC_RELAXED, __HIP_MEMORY_SCOPE_SYSTEM);
        if (a >= t1 && b >= t2) break;
        __builtin_amdgcn_s_sleep(2);
        if (++spins > SPIN_CAP) break;       // watchdog
    }
    asm volatile("" ::: "memory");
}
__device__ __forceinline__ void post_prog(unsigned* p, int v) {
    __hip_atomic_store(p, (unsigned)v, __ATOMIC_RELAXED, __HIP_MEMORY_SCOPE_SYSTEM);
}
__device__ __forceinline__ unsigned ld_u32_coh(const unsigned* p) {
    return __hip_atomic_load((unsigned*)p, __ATOMIC_RELAXED, __HIP_MEMORY_SCOPE_SYSTEM);
}
__device__ __forceinline__ void st_u32_coh(unsigned* p, unsigned v) {
    __hip_atomic_store(p, v, __ATOMIC_RELAXED, __HIP_MEMORY_SCOPE_SYSTEM);
}
__device__ __forceinline__ u64 ld_u64_coh(const u64* p) {
    return __hip_atomic_load((u64*)p, __ATOMIC_RELAXED, __HIP_MEMORY_SCOPE_SYSTEM);
}
__device__ __forceinline__ void st_u64_coh(u64* p, u64 v) {
    __hip_atomic_store(p, v, __ATOMIC_RELAXED, __HIP_MEMORY_SCOPE_SYSTEM);
}
#define CFENCE() asm volatile("" ::: "memory")

// =============== persistent 4-stage pipeline, 2 clusters per WG ===============
__global__ void __launch_bounds__(512, 1)
gru_pipe(const float* __restrict__ x,
         const float* __restrict__ wih1, const float* __restrict__ whh1,
         const float* __restrict__ bih1, const float* __restrict__ bhh1,
         const float* __restrict__ wih2, const float* __restrict__ whh2,
         const float* __restrict__ bih2, const float* __restrict__ bhh2,
         char* __restrict__ ws)
{
    const int tid = threadIdx.x, wave = tid >> 6, lane = tid & 63;
    const int qd = lane >> 4, ln = lane & 15;
    const int stage = blockIdx.x & 3;
    const int pr_id = blockIdx.x >> 2;       // 0..15
    const int cl0   = pr_id * 2;

    unsigned* prog = (unsigned*)(ws + OFF_PROG) + pr_id * 4;
    short* h2seq = (short*)(ws + OFF_H2SEQ);

    __shared__ __align__(16) short hb[2][2][16][HPAD];   // [cluster][buf][row][col]
    {   // zero; garbage row-slots must stay 0 forever
        short* z = &hb[0][0][0][0];
        for (int i = tid; i < 2*2*16*HPAD; i += 512) z[i] = 0;
    }
    __syncthreads();

    if (stage == 0) {
        // ================= M1: gi1 producer, 2 clusters =================
        bf16x8 Wi[2][3][4]; f32x4 cinit[2][3];
        #pragma unroll
        for (int b2 = 0; b2 < 2; ++b2)
        #pragma unroll
        for (int g = 0; g < 3; ++g) {
            const int grow = g*256 + (wave*2 + b2)*16 + ln;
            #pragma unroll
            for (int kc = 0; kc < 4; ++kc)
                Wi[b2][g][kc] = ldfrag_f32(wih1 + grow*II + kc*32 + qd*8);
            float c0 = bih1[grow] + (g < 2 ? bhh1[grow] : 0.f);
            cinit[b2][g] = f32x4{c0, c0, c0, c0};
        }
        const int rr = (ln>>2)*2 + (ln&1);
        const float* xr[2];
        xr[0] = x + (size_t)((cl0 + 0)*RPC + rr) * (TT*II) + qd*8;
        xr[1] = x + (size_t)((cl0 + 1)*RPC + rr) * (TT*II) + qd*8;
        float4 xf[2][8];
        #pragma unroll
        for (int cc = 0; cc < 2; ++cc)
        #pragma unroll
        for (int kc = 0; kc < 4; ++kc) {
            xf[cc][2*kc]   = *(const float4*)(xr[cc] + kc*32);
            xf[cc][2*kc+1] = *(const float4*)(xr[cc] + kc*32 + 4);
        }

        for (int t = 0; t < TT; ++t) {
            if ((t & 7) == 0) poll_ge(&prog[P_A], t - 24);   // gi1 ring backpressure
            CFENCE();
            #pragma unroll
            for (int cc = 0; cc < 2; ++cc) {
                bf16x8 a[4];
                #pragma unroll
                for (int kc = 0; kc < 4; ++kc) {
                    float4 u = xf[cc][2*kc], v = xf[cc][2*kc+1];
                    bf16x8 f;
                    f[0]=f2bf(u.x); f[1]=f2bf(u.y); f[2]=f2bf(u.z); f[3]=f2bf(u.w);
                    f[4]=f2bf(v.x); f[5]=f2bf(v.y); f[6]=f2bf(v.z); f[7]=f2bf(v.w);
                    a[kc] = f;
                }
                if (t + 1 < TT) {
                    const float* xn = xr[cc] + (size_t)(t+1)*II;
                    #pragma unroll
                    for (int kc = 0; kc < 4; ++kc) {
                        xf[cc][2*kc]   = *(const float4*)(xn + kc*32);
                        xf[cc][2*kc+1] = *(const float4*)(xn + kc*32 + 4);
                    }
                }
                CFENCE();
                f32x4 acc[2][3];
                #pragma unroll
                for (int b2 = 0; b2 < 2; ++b2)
                #pragma unroll
                for (int g = 0; g < 3; ++g) acc[b2][g] = cinit[b2][g];
                #pragma unroll
                for (int kc = 0; kc < 4; ++kc)
                #pragma unroll
                for (int b2 = 0; b2 < 2; ++b2)
                #pragma unroll
                for (int g = 0; g < 3; ++g)
                    acc[b2][g] = __builtin_amdgcn_mfma_f32_16x16x32_bf16(a[kc], Wi[b2][g][kc], acc[b2][g], 0, 0, 0);
                CFENCE();
                char* slot = ws + OFF_GI1 + ((size_t)(cl0+cc)*RD + (t & (RD-1)))*GI_SLOT;
                #pragma unroll
                for (int b2 = 0; b2 < 2; ++b2) {
                    u64* tp = (u64*)(slot + (wave*2 + b2)*1024);
                    u64 rz = (u64)pk2bf(acc[b2][0][0], acc[b2][0][1])
                           | ((u64)pk2bf(acc[b2][1][0], acc[b2][1][1]) << 32);
                    st_u64_coh(tp + lane, rz);
                    union { float f[2]; u64 u; } np;
                    np.f[0] = acc[b2][2][0]; np.f[1] = acc[b2][2][1];
                    st_u64_coh(tp + 64 + lane, np.u);
                }
                CFENCE();
            }
            if (t & 1) {   // prove stores(t-1) complete, then post t-1
                asm volatile("s_waitcnt vmcnt(24)" ::: "memory");
                if (tid == 0) post_prog(&prog[P_M1], t - 1);
            }
            __builtin_amdgcn_sched_barrier(0);
            __builtin_amdgcn_s_barrier();
        }
        asm volatile("s_waitcnt vmcnt(0)" ::: "memory");
        __syncthreads();
        if (tid == 0) post_prog(&prog[P_M1], 1000000);

    } else if (stage == 1) {
        // ================= A: layer-1 recurrence, 2 clusters =================
        bf16x8 Wh[2][3][8]; float bnn[2];
        #pragma unroll
        for (int b2 = 0; b2 < 2; ++b2) {
            const int colg = (wave*2 + b2)*16 + ln;
            #pragma unroll
            for (int g = 0; g < 3; ++g)
                #pragma unroll
                for (int kc = 0; kc < 8; ++kc)
                    Wh[b2][g][kc] = ldfrag_f32(whh1 + (g*256 + colg)*HH + kc*32 + qd*8);
            bnn[b2] = bhh1[512 + colg];
        }
        float hold[2][2][2] = {};
        u64 prz[2][2], pn[2][2];

        poll_ge(&prog[P_M1], 2);
        #pragma unroll
        for (int cc = 0; cc < 2; ++cc) {
            char* slot = ws + OFF_GI1 + (size_t)(cl0+cc)*RD*GI_SLOT;
            #pragma unroll
            for (int b2 = 0; b2 < 2; ++b2) {
                const u64* tp = (const u64*)(slot + (wave*2 + b2)*1024);
                prz[cc][b2] = ld_u64_coh(tp + lane);
                pn [cc][b2] = ld_u64_coh(tp + 64 + lane);
            }
        }

        for (int t = 0; t < TT; ++t) {
            if ((t & 7) == 0) poll2_ge(&prog[P_M1], t + 10, &prog[P_M2], t - 24);
            CFENCE();
            const int rb = (t + 1) & 1, wb = t & 1;
            #pragma unroll
            for (int cc = 0; cc < 2; ++cc) {
                // consume prefetched gi1(t)
                f32x4 aR[2], aZ[2], aN[2]; float gn[2][2];
                #pragma unroll
                for (int b2 = 0; b2 < 2; ++b2) {
                    unsigned rzl = (unsigned)prz[cc][b2];
                    unsigned rzh = (unsigned)(prz[cc][b2] >> 32);
                    aR[b2] = f32x4{bf2f_lo(rzl), bf2f_hi(rzl), 0.f, 0.f};
                    aZ[b2] = f32x4{bf2f_lo(rzh), bf2f_hi(rzh), 0.f, 0.f};
                    union { u64 u; float f[2]; } c; c.u = pn[cc][b2];
                    gn[b2][0] = c.f[0]; gn[b2][1] = c.f[1];
                    aN[b2] = f32x4{bnn[b2], bnn[b2], 0.f, 0.f};
                }
                // prefetch gi1(t+1) for this cluster
                if (t + 1 < TT) {
                    char* slot = ws + OFF_GI1 + ((size_t)(cl0+cc)*RD + ((t+1) & (RD-1)))*GI_SLOT;
                    #pragma unroll
                    for (int b2 = 0; b2 < 2; ++b2) {
                        const u64* tp = (const u64*)(slot + (wave*2 + b2)*1024);
                        prz[cc][b2] = ld_u64_coh(tp + lane);
                        pn [cc][b2] = ld_u64_coh(tp + 64 + lane);
                    }
                }
                CFENCE();
                #pragma unroll
                for (int kc = 0; kc < 8; ++kc) {
                    bf16x8 f = *(const bf16x8*)&hb[cc][rb][ln][kc*32 + qd*8];
                    aR[0] = __builtin_amdgcn_mfma_f32_16x16x32_bf16(f, Wh[0][0][kc], aR[0], 0,0,0);
                    aR[1] = __builtin_amdgcn_mfma_f32_16x16x32_bf16(f, Wh[1][0][kc], aR[1], 0,0,0);
                    aZ[0] = __builtin_amdgcn_mfma_f32_16x16x32_bf16(f, Wh[0][1][kc], aZ[0], 0,0,0);
                    aZ[1] = __builtin_amdgcn_mfma_f32_16x16x32_bf16(f, Wh[1][1][kc], aZ[1], 0,0,0);
                    aN[0] = __builtin_amdgcn_mfma_f32_16x16x32_bf16(f, Wh[0][2][kc], aN[0], 0,0,0);
                    aN[1] = __builtin_amdgcn_mfma_f32_16x16x32_bf16(f, Wh[1][2][kc], aN[1], 0,0,0);
                }
                CFENCE();
                unsigned* h1slot = (unsigned*)(ws + OFF_H1R + ((size_t)(cl0+cc)*RD + (t & (RD-1)))*4096u);
                #pragma unroll
                for (int b2 = 0; b2 < 2; ++b2) {
                    const int colg = (wave*2 + b2)*16 + ln;
                    unsigned pk = 0;
                    #pragma unroll
                    for (int r = 0; r < 2; ++r) {
                        float rg = sigm_f(aR[b2][r]);
                        float zg = sigm_f(aZ[b2][r]);
                        float ng = tanh_f(gn[b2][r] + rg * aN[b2][r]);
                        float h  = (1.f - zg)*ng + zg*hold[cc][b2][r];
                        hold[cc][b2][r] = h;
                        short hs = f2bf(h);
                        hb[cc][wb][qd*4 + r][colg] = hs;
                        pk |= (unsigned)(unsigned short)hs << (16*r);
                    }
                    st_u32_coh(h1slot + colg*4 + qd, pk);
                }
                CFENCE();
            }
            if (t & 1) {
                asm volatile("s_waitcnt vmcnt(12)" ::: "memory");
                if (tid == 0) post_prog(&prog[P_A], t - 1);
            }
            asm volatile("s_waitcnt lgkmcnt(0)" ::: "memory");
            __builtin_amdgcn_sched_barrier(0);
            __builtin_amdgcn_s_barrier();
        }
        asm volatile("s_waitcnt vmcnt(0)" ::: "memory");
        __syncthreads();
        if (tid == 0) post_prog(&prog[P_A], 1000000);

    } else if (stage == 2) {
        // ================= M2: gi2 = h1 @ Wih2^T, 2 clusters =================
        bf16x8 Wi[2][3][8]; float c0s[2][3];
        #pragma unroll
        for (int b2 = 0; b2 < 2; ++b2)
        #pragma unroll
        for (int g = 0; g < 3; ++g) {
            const int grow = g*256 + (wave*2 + b2)*16 + ln;
            #pragma unroll
            for (int kc = 0; kc < 8; ++kc)
                Wi[b2][g][kc] = ldfrag_f32(wih2 + grow*HH + kc*32 + qd*8);
            c0s[b2][g] = bih2[grow] + (g < 2 ? bhh2[grow] : 0.f);
        }
        const int base = (tid & 1) * 8, pcol = tid >> 1;
        u64 vc[2];

        poll_ge(&prog[P_A], 2);
        #pragma unroll
        for (int cc = 0; cc < 2; ++cc) {
            const u64* h1s = (const u64*)(ws + OFF_H1R + (size_t)(cl0+cc)*RD*4096u);
            u64 v = ld_u64_coh(h1s + tid);
            unsigned lo = (unsigned)v, hi = (unsigned)(v >> 32);
            hb[cc][0][base + 0][pcol] = (short)lo;
            hb[cc][0][base + 1][pcol] = (short)(lo >> 16);
            hb[cc][0][base + 4][pcol] = (short)hi;
            hb[cc][0][base + 5][pcol] = (short)(hi >> 16);
            vc[cc] = ld_u64_coh((const u64*)(ws + OFF_H1R + ((size_t)(cl0+cc)*RD + 1)*4096u) + tid);
        }
        __syncthreads();

        for (int u = 0; u < TT; ++u) {
            if ((u & 7) == 0) poll2_ge(&prog[P_A], u + 11, &prog[P_B], u - 24);
            CFENCE();
            #pragma unroll
            for (int cc = 0; cc < 2; ++cc) {
                if (u + 1 < TT) {       // unpack h1(u+1), loaded last superstep
                    unsigned lo = (unsigned)vc[cc], hi = (unsigned)(vc[cc] >> 32);
                    hb[cc][(u+1) & 1][base + 0][pcol] = (short)lo;
                    hb[cc][(u+1) & 1][base + 1][pcol] = (short)(lo >> 16);
                    hb[cc][(u+1) & 1][base + 4][pcol] = (short)hi;
                    hb[cc][(u+1) & 1][base + 5][pcol] = (short)(hi >> 16);
                }
                if (u + 2 < TT)
                    vc[cc] = ld_u64_coh((const u64*)(ws + OFF_H1R + ((size_t)(cl0+cc)*RD + ((u+2) & (RD-1)))*4096u) + tid);
            }
            CFENCE();
            #pragma unroll
            for (int cc = 0; cc < 2; ++cc) {
                f32x4 acc[2][3];
                #pragma unroll
                for (int b2 = 0; b2 < 2; ++b2)
                #pragma unroll
                for (int g = 0; g < 3; ++g) {
                    float c0 = c0s[b2][g];
                    acc[b2][g] = f32x4{c0, c0, c0, c0};
                }
                #pragma unroll
                for (int kc = 0; kc < 8; ++kc) {
                    bf16x8 f = *(const bf16x8*)&hb[cc][u & 1][ln][kc*32 + qd*8];
                    #pragma unroll
                    for (int b2 = 0; b2 < 2; ++b2)
                    #pragma unroll
                    for (int g = 0; g < 3; ++g)
                        acc[b2][g] = __builtin_amdgcn_mfma_f32_16x16x32_bf16(f, Wi[b2][g][kc], acc[b2][g], 0, 0, 0);
                }
                CFENCE();
                char* slot = ws + OFF_GI2 + ((size_t)(cl0+cc)*RD + (u & (RD-1)))*GI_SLOT;
                #pragma unroll
                for (int b2 = 0; b2 < 2; ++b2) {
                    u64* tp = (u64*)(slot + (wave*2 + b2)*1024);
                    u64 rz = (u64)pk2bf(acc[b2][0][0], acc[b2][0][1])
                           | ((u64)pk2bf(acc[b2][1][0], acc[b2][1][1]) << 32);
                    st_u64_coh(tp + lane, rz);
                    union { float f[2]; u64 u2; } np;
                    np.f[0] = acc[b2][2][0]; np.f[1] = acc[b2][2][1];
                    st_u64_coh(tp + 64 + lane, np.u2);
                }
                CFENCE();
            }
            if (u & 1) {
                asm volatile("s_waitcnt vmcnt(10)" ::: "memory");
                if (tid == 0) post_prog(&prog[P_M2], u - 1);
            }
            asm volatile("s_waitcnt lgkmcnt(0)" ::: "memory");
            __builtin_amdgcn_sched_barrier(0);
            __builtin_amdgcn_s_barrier();
        }
        asm volatile("s_waitcnt vmcnt(0)" ::: "memory");
        __syncthreads();
        if (tid == 0) post_prog(&prog[P_M2], 1000000);

    } else {
        // ================= B: layer-2 recurrence + h2seq + BN, 2 clusters =====
        bf16x8 Wh[2][3][8]; float bnn[2];
        #pragma unroll
        for (int b2 = 0; b2 < 2; ++b2) {
            const int colg = (wave*2 + b2)*16 + ln;
            #pragma unroll
            for (int g = 0; g < 3; ++g)
                #pragma unroll
                for (int kc = 0; kc < 8; ++kc)
                    Wh[b2][g][kc] = ldfrag_f32(whh2 + (g*256 + colg)*HH + kc*32 + qd*8);
            bnn[b2] = bhh2[512 + colg];
        }
        float* bnsum = (float*)(ws + OFF_BNSUM);
        float* bnsq  = (float*)(ws + OFF_BNSQ);
        float hold[2][2][2] = {};
        float cbs[2][2] = {}, cbq[2][2] = {};
        u64 prz[2][2], pn[2][2];

        poll_ge(&prog[P_M2], 2);
        #pragma unroll
        for (int cc = 0; cc < 2; ++cc) {
            char* slot = ws + OFF_GI2 + (size_t)(cl0+cc)*RD*GI_SLOT;
            #pragma unroll
            for (int b2 = 0; b2 < 2; ++b2) {
                const u64* tp = (const u64*)(slot + (wave*2 + b2)*1024);
                prz[cc][b2] = ld_u64_coh(tp + lane);
                pn [cc][b2] = ld_u64_coh(tp + 64 + lane);
            }
        }
        __syncthreads();

        for (int v = 0; v < TT; ++v) {
            if ((v & 7) == 0) poll_ge(&prog[P_M2], v + 10);
            CFENCE();
            const int rb = (v + 1) & 1, wb = v & 1;
            #pragma unroll
            for (int cc = 0; cc < 2; ++cc) {
                f32x4 aR[2], aZ[2], aN[2]; float gn[2][2];
                #pragma unroll
                for (int b2 = 0; b2 < 2; ++b2) {
                    unsigned rzl = (unsigned)prz[cc][b2];
                    unsigned rzh = (unsigned)(prz[cc][b2] >> 32);
                    aR[b2] = f32x4{bf2f_lo(rzl), bf2f_hi(rzl), 0.f, 0.f};
                    aZ[b2] = f32x4{bf2f_lo(rzh), bf2f_hi(rzh), 0.f, 0.f};
                    union { u64 u; float f[2]; } c; c.u = pn[cc][b2];
                    gn[b2][0] = c.f[0]; gn[b2][1] = c.f[1];
                    aN[b2] = f32x4{bnn[b2], bnn[b2], 0.f, 0.f};
                }
                if (v + 1 < TT) {
                    char* slot = ws + OFF_GI2 + ((size_t)(cl0+cc)*RD + ((v+1) & (RD-1)))*GI_SLOT;
                    #pragma unroll
                    for (int b2 = 0; b2 < 2; ++b2) {
                        const u64* tp = (const u64*)(slot + (wave*2 + b2)*1024);
                        prz[cc][b2] = ld_u64_coh(tp + lane);
                        pn [cc][b2] = ld_u64_coh(tp + 64 + lane);
                    }
                }
                CFENCE();
                #pragma unroll
                for (int kc = 0; kc < 8; ++kc) {
                    bf16x8 f = *(const bf16x8*)&hb[cc][rb][ln][kc*32 + qd*8];
                    aR[0] = __builtin_amdgcn_mfma_f32_16x16x32_bf16(f, Wh[0][0][kc], aR[0], 0,0,0);
                    aR[1] = __builtin_amdgcn_mfma_f32_16x16x32_bf16(f, Wh[1][0][kc], aR[1], 0,0,0);
                    aZ[0] = __builtin_amdgcn_mfma_f32_16x16x32_bf16(f, Wh[0][1][kc], aZ[0], 0,0,0);
                    aZ[1] = __builtin_amdgcn_mfma_f32_16x16x32_bf16(f, Wh[1][1][kc], aZ[1], 0,0,0);
                    aN[0] = __builtin_amdgcn_mfma_f32_16x16x32_bf16(f, Wh[0][2][kc], aN[0], 0,0,0);
                    aN[1] = __builtin_amdgcn_mfma_f32_16x16x32_bf16(f, Wh[1][2][kc], aN[1], 0,0,0);
                }
                CFENCE();
                const int grow0c = (cl0 + cc) * RPC;
                #pragma unroll
                for (int b2 = 0; b2 < 2; ++b2) {
                    const int colg = (wave*2 + b2)*16 + ln;
                    #pragma unroll
                    for (int r = 0; r < 2; ++r) {
                        float rg = sigm_f(aR[b2][r]);
                        float zg = sigm_f(aZ[b2][r]);
                        float ng = tanh_f(gn[b2][r] + rg * aN[b2][r]);
                        float h  = (1.f - zg)*ng + zg*hold[cc][b2][r];
                        hold[cc][b2][r] = h;
                        cbs[cc][b2] += h; cbq[cc][b2] += h*h;
                        short hs = f2bf(h);
                        hb[cc][wb][qd*4 + r][colg] = hs;
                        h2seq[((size_t)v*BB + grow0c + qd*2 + r)*HH + colg] = hs;
                    }
                }
                CFENCE();
            }
            if ((v & 1) && tid == 0) post_prog(&prog[P_B], v - 1);
            asm volatile("s_waitcnt lgkmcnt(0)" ::: "memory");
            __builtin_amdgcn_sched_barrier(0);
            __builtin_amdgcn_s_barrier();
        }
        #pragma unroll
        for (int cc = 0; cc < 2; ++cc)
        #pragma unroll
        for (int b2 = 0; b2 < 2; ++b2) {
            const int colg = (wave*2 + b2)*16 + ln;
            atomicAdd(&bnsum[colg], cbs[cc][b2]);
            atomicAdd(&bnsq[colg],  cbq[cc][b2]);
        }
        __syncthreads();
        if (tid == 0) post_prog(&prog[P_B], 1000000);
    }
}

// ---------------- BN finalize + hardtanh + temporal mean + FC ----------------
__global__ void gru_final(const char* __restrict__ ws,
                          const float* __restrict__ gamma, const float* __restrict__ beta,
                          const float* __restrict__ fcw, const float* __restrict__ fcb,
                          float* __restrict__ out)
{
    __shared__ float summ[HH];
    const int b = blockIdx.x, c = threadIdx.x;
    const float* bnsum = (const float*)(ws + OFF_BNSUM);
    const float* bnsq  = (const float*)(ws + OFF_BNSQ);
    const short* h2seq = (const short*)(ws + OFF_H2SEQ);

    const float inv = 1.f / (float)(BB * TT);
    float mean = bnsum[c] * inv;
    float var  = bnsq[c] * inv - mean * mean;
    float scale = rsqrtf(var + EPSV) * gamma[c];
    float shift = beta[c] - mean * scale;

    const short* p = h2seq + (size_t)b*HH + c;    // [t][b][h]
    float acc = 0.f;
    #pragma unroll 4
    for (int t = 0; t < TT; ++t) {
        float v = bf2f(p[(size_t)t*BB*HH]) * scale + shift;
        v = fminf(fmaxf(v, -2.f), 2.f);
        acc += v;
    }
    summ[c] = acc * (1.f / TT);
    __syncthreads();
    if (c < OUTD) {
        float d = fcb[c];
        const float* wr = fcw + c*HH;
        #pragma unroll 8
        for (int h = 0; h < HH; ++h) d += wr[h] * summ[h];
        out[b*OUTD + c] = d;
    }
}

extern "C" void kernel_launch(void* const* d_in, const int* in_sizes, int n_in,
                              void* d_out, int out_size, void* d_ws, size_t ws_size,
                              hipStream_t stream)
{
    const float* x    = (const float*)d_in[0];
    const float* wih1 = (const float*)d_in[1];
    const float* whh1 = (const float*)d_in[2];
    const float* bih1 = (const float*)d_in[3];
    const float* bhh1 = (const float*)d_in[4];
    const float* wih2 = (const float*)d_in[5];
    const float* whh2 = (const float*)d_in[6];
    const float* bih2 = (const float*)d_in[7];
    const float* bhh2 = (const float*)d_in[8];
    const float* gamma= (const float*)d_in[9];
    const float* beta = (const float*)d_in[10];
    const float* fcw  = (const float*)d_in[11];
    const float* fcb  = (const float*)d_in[12];
    char* ws = (char*)d_ws;

    // progress counters + BN accumulators start at 0 (re-zeroed every replay)
    (void)hipMemsetAsync(ws, 0, OFF_ZERO_END, stream);

    // 16 pairs x 4 stages = 64 co-resident WGs (one per CU), 2 clusters per WG
    hipLaunchKernelGGL(gru_pipe, dim3(NPAIR*4), dim3(512), 0, stream,
                       x, wih1, whh1, bih1, bhh1, wih2, whh2, bih2, bhh2, ws);

    hipLaunchKernelGGL(gru_final, dim3(BB), dim3(HH), 0, stream,
                       (const char*)ws, gamma, beta, fcw, fcb, (float*)d_out);
}

// Round 8
// 3061.970 us; speedup vs baseline: 1.1723x; 1.1723x over previous
//
#include <hip/hip_runtime.h>
#include <stdint.h>

// ---------------- problem constants ----------------
#define TT 512
#define BB 256
#define HH 256
#define II 128
#define OUTD 128
#define EPSV 1e-5f

// ---------------- geometry ----------------
// v9: 32 clusters x 8 rows, 4 stages (M1,A,M2,B) x 1 WG(512thr)/cluster = 128 WGs.
// Root cause fixed here (v4/v5/v8 all pinned at ~3.4us/step): their end-of-iter
// counted vmcnt drained ops issued ONE iteration earlier -> period = uncached
// store/load round-trip. v9 uses a DEPTH-4 pipeline: 4 named register sets,
// unroll-by-4; loads for step T+4 issued at T; end-of-iter vmcnt(N) forces only
// loads issued 3 iters ago + stores issued 4 iters ago:
//   per-iter ops (ld,st): M1 (8,4) N=36 | A (4,2) N=18 | M2 (1,4) N=15 | B (4,4) N=24
//   (N = ops newer than the target minus current-iter stores, as reorder margin)
// Posts: value t-5 at top of iter t (stores(t-5) proven by the lag-4 proof at
// end of t-1; all waves barrier-synced). Polls every 8:
//   forward: consumer at t requires producer post >= t+12 (covers issues
//            t..t+7 targeting slots <= t+12)
//   back:    producer at t requires consumer post >= t-24
// Feasibility: forward needs skew >= 17; backpressure caps skew <= 19 (+7
// drift = 26); ring RD=32 aliasing needs skew <= ~30. Band [17,26] nonempty.
// Tail: last 8 iters use vmcnt(0) (counted-N goes vacuous when issues stop).
#define NCL 32
#define RPC 8
#define RD  32
#define HPAD 264
#define SPIN_CAP (1 << 17)

#define P_M1 0
#define P_A  1
#define P_M2 2
#define P_B  3

// ---------------- workspace layout (bytes), total ~100 MB ----------------
#define OFF_PROG     0u
#define OFF_BNSUM    1024u
#define OFF_BNSQ     2048u
#define OFF_ZERO_END 3072u
#define OFF_GI1      65536u
#define GI_SLOT      16384u                       // 16 tiles x (rz u64[64] | n u64[64])
#define GI1_BYTES    ((unsigned)NCL*RD*GI_SLOT)   // 16 MB
#define OFF_H1R      (OFF_GI1 + GI1_BYTES)
#define H1R_BYTES    ((unsigned)NCL*RD*4096u)     // 4 MB
#define OFF_GI2      (OFF_H1R + H1R_BYTES)
#define GI2_BYTES    ((unsigned)NCL*RD*GI_SLOT)   // 16 MB
#define OFF_H2SEQ    (OFF_GI2 + GI2_BYTES)        // 64 MB bf16 [t][b][h]

typedef short bf16x8 __attribute__((ext_vector_type(8)));
typedef float f32x4  __attribute__((ext_vector_type(4)));
typedef unsigned long long u64;

__device__ __forceinline__ short f2bf(float v) {
    unsigned u = __float_as_uint(v);
    u += 0x7fffu + ((u >> 16) & 1u);
    return (short)(u >> 16);
}
__device__ __forceinline__ float bf2f(short s) {
    return __uint_as_float(((unsigned)(unsigned short)s) << 16);
}
__device__ __forceinline__ float bf2f_lo(unsigned u) { return __uint_as_float(u << 16); }
__device__ __forceinline__ float bf2f_hi(unsigned u) { return __uint_as_float(u & 0xffff0000u); }
__device__ __forceinline__ unsigned pk2bf(float a, float b) {
    return (unsigned)(unsigned short)f2bf(a) | ((unsigned)(unsigned short)f2bf(b) << 16);
}
__device__ __forceinline__ bf16x8 ldfrag_f32(const float* __restrict__ p) {
    const float4* q = (const float4*)p;
    float4 a = q[0], b = q[1];
    bf16x8 f;
    f[0]=f2bf(a.x); f[1]=f2bf(a.y); f[2]=f2bf(a.z); f[3]=f2bf(a.w);
    f[4]=f2bf(b.x); f[5]=f2bf(b.y); f[6]=f2bf(b.z); f[7]=f2bf(b.w);
    return f;
}
__device__ __forceinline__ float sigm_f(float x) {
    float e = __expf(-x);
    return __builtin_amdgcn_rcpf(1.f + e);
}
__device__ __forceinline__ float tanh_f(float x) {
    float ax = fabsf(x);
    float e  = __expf(-2.f * ax);
    float t  = (1.f - e) * __builtin_amdgcn_rcpf(1.f + e);
    return copysignf(t, x);
}
__device__ __forceinline__ void poll_ge(const unsigned* p, int tgt) {
    if (tgt <= 0) return;
    int spins = 0;
    while ((int)__hip_atomic_load((unsigned*)p, __ATOMIC_RELAXED, __HIP_MEMORY_SCOPE_SYSTEM) < tgt) {
        __builtin_amdgcn_s_sleep(2);
        if (++spins > SPIN_CAP) break;       // watchdog
    }
    asm volatile("" ::: "memory");
}
__device__ __forceinline__ void poll2_ge(const unsigned* p1, int t1, const unsigned* p2, int t2) {
    int spins = 0;
    for (;;) {
        int a = (int)__hip_atomic_load((unsigned*)p1, __ATOMIC_RELAXED, __HIP_MEMORY_SCOPE_SYSTEM);
        int b = (int)__hip_atomic_load((unsigned*)p2, __ATOMIC_RELAXED, __HIP_MEMORY_SCOPE_SYSTEM);
        if (a >= t1 && b >= t2) break;
        __builtin_amdgcn_s_sleep(2);
        if (++spins > SPIN_CAP) break;       // watchdog
    }
    asm volatile("" ::: "memory");
}
__device__ __forceinline__ void post_prog(unsigned* p, int v) {
    __hip_atomic_store(p, (unsigned)v, __ATOMIC_RELAXED, __HIP_MEMORY_SCOPE_SYSTEM);
}
__device__ __forceinline__ u64 ld_u64_coh(const u64* p) {
    return __hip_atomic_load((u64*)p, __ATOMIC_RELAXED, __HIP_MEMORY_SCOPE_SYSTEM);
}
__device__ __forceinline__ void st_u64_coh(u64* p, u64 v) {
    __hip_atomic_store(p, v, __ATOMIC_RELAXED, __HIP_MEMORY_SCOPE_SYSTEM);
}
__device__ __forceinline__ void st_u32_coh(unsigned* p, unsigned v) {
    __hip_atomic_store(p, v, __ATOMIC_RELAXED, __HIP_MEMORY_SCOPE_SYSTEM);
}
#define CFENCE() asm volatile("" ::: "memory")
#define WAITV(n)  asm volatile("s_waitcnt vmcnt(" #n ")" ::: "memory")
#define WAITV0()  asm volatile("s_waitcnt vmcnt(0)" ::: "memory")
#define WAITL0()  asm volatile("s_waitcnt lgkmcnt(0)" ::: "memory")
#define ENDBAR()  do { __builtin_amdgcn_sched_barrier(0); __builtin_amdgcn_s_barrier(); } while (0)

// =============== persistent 4-stage pipeline, depth-4 pipelined rings ==========
__global__ void __launch_bounds__(512, 1)
gru_pipe(const float* __restrict__ x,
         const float* __restrict__ wih1, const float* __restrict__ whh1,
         const float* __restrict__ bih1, const float* __restrict__ bhh1,
         const float* __restrict__ wih2, const float* __restrict__ whh2,
         const float* __restrict__ bih2, const float* __restrict__ bhh2,
         char* __restrict__ ws)
{
    const int tid = threadIdx.x, wave = tid >> 6, lane = tid & 63;
    const int qd = lane >> 4, ln = lane & 15;
    const int stage = blockIdx.x & 3;
    const int cl    = blockIdx.x >> 2;
    const int grow0 = cl * RPC;
    const int tile0 = wave*2, tile1 = wave*2 + 1;

    unsigned* prog = (unsigned*)(ws + OFF_PROG) + cl * 4;
    short* h2seq = (short*)(ws + OFF_H2SEQ);

    __shared__ __align__(16) short hb[2][16][HPAD];
    {   // zero both buffers; garbage row-slots must stay 0 forever
        short* z = &hb[0][0][0];
        for (int i = tid; i < 2*16*HPAD; i += 512) z[i] = 0;
    }
    __syncthreads();

    if (stage == 0) {
        // ================= M1: gi1 = x@Wih1^T (free-running) =================
        bf16x8 Wi[2][3][4]; f32x4 cinit[2][3];
        #pragma unroll
        for (int b2 = 0; b2 < 2; ++b2)
        #pragma unroll
        for (int g = 0; g < 3; ++g) {
            const int grow = g*256 + (wave*2 + b2)*16 + ln;
            #pragma unroll
            for (int kc = 0; kc < 4; ++kc)
                Wi[b2][g][kc] = ldfrag_f32(wih1 + grow*II + kc*32 + qd*8);
            float c0 = bih1[grow] + (g < 2 ? bhh1[grow] : 0.f);
            cinit[b2][g] = f32x4{c0, c0, c0, c0};
        }
        const float* xr = x + (size_t)(grow0 + (ln>>2)*2 + (ln&1)) * (TT*II) + qd*8;
        float4 xf0[8], xf1[8], xf2[8], xf3[8];

#define M1_PRO(S) { const float* xp = xr + (size_t)(S)*II;                     \
        _Pragma("unroll")                                                      \
        for (int kc = 0; kc < 4; ++kc) {                                       \
            xf##S[2*kc]   = *(const float4*)(xp + kc*32);                      \
            xf##S[2*kc+1] = *(const float4*)(xp + kc*32 + 4);                   \
        } }
        M1_PRO(0) M1_PRO(1) M1_PRO(2) M1_PRO(3)
#undef M1_PRO
        WAITV0();

#define M1_BODY(T, S)                                                          \
        {                                                                      \
            if (tid == 0 && (T) >= 5) post_prog(&prog[P_M1], (T) - 5);         \
            if (((T) & 7) == 0) poll_ge(&prog[P_A], (T) - 24);                 \
            CFENCE();                                                          \
            bf16x8 a[4];                                                       \
            _Pragma("unroll")                                                  \
            for (int kc = 0; kc < 4; ++kc) {                                   \
                float4 u = xf##S[2*kc], v = xf##S[2*kc+1];                     \
                bf16x8 f;                                                      \
                f[0]=f2bf(u.x); f[1]=f2bf(u.y); f[2]=f2bf(u.z); f[3]=f2bf(u.w);\
                f[4]=f2bf(v.x); f[5]=f2bf(v.y); f[6]=f2bf(v.z); f[7]=f2bf(v.w);\
                a[kc] = f;                                                     \
            }                                                                  \
            if ((T) + 4 < TT) {                                                \
                const float* xn = xr + (size_t)((T)+4)*II;                     \
                _Pragma("unroll")                                              \
                for (int kc = 0; kc < 4; ++kc) {                               \
                    xf##S[2*kc]   = *(const float4*)(xn + kc*32);              \
                    xf##S[2*kc+1] = *(const float4*)(xn + kc*32 + 4);          \
                }                                                              \
            }                                                                  \
            CFENCE();                                                          \
            f32x4 acc[2][3];                                                   \
            _Pragma("unroll")                                                  \
            for (int b2 = 0; b2 < 2; ++b2)                                     \
            _Pragma("unroll")                                                  \
            for (int g = 0; g < 3; ++g) acc[b2][g] = cinit[b2][g];             \
            _Pragma("unroll")                                                  \
            for (int kc = 0; kc < 4; ++kc)                                     \
            _Pragma("unroll")                                                  \
            for (int b2 = 0; b2 < 2; ++b2)                                     \
            _Pragma("unroll")                                                  \
            for (int g = 0; g < 3; ++g)                                        \
                acc[b2][g] = __builtin_amdgcn_mfma_f32_16x16x32_bf16(a[kc], Wi[b2][g][kc], acc[b2][g], 0, 0, 0); \
            CFENCE();                                                          \
            char* slot = ws + OFF_GI1 + ((size_t)cl*RD + ((T) & (RD-1)))*GI_SLOT; \
            {                                                                  \
                u64* t0p = (u64*)(slot + tile0*1024);                          \
                u64 rz = (u64)pk2bf(acc[0][0][0], acc[0][0][1])                \
                       | ((u64)pk2bf(acc[0][1][0], acc[0][1][1]) << 32);       \
                st_u64_coh(t0p + lane, rz);                                    \
                union { float f[2]; u64 u; } np;                               \
                np.f[0] = acc[0][2][0]; np.f[1] = acc[0][2][1];                \
                st_u64_coh(t0p + 64 + lane, np.u);                             \
                u64* t1p = (u64*)(slot + tile1*1024);                          \
                rz = (u64)pk2bf(acc[1][0][0], acc[1][0][1])                    \
                   | ((u64)pk2bf(acc[1][1][0], acc[1][1][1]) << 32);           \
                st_u64_coh(t1p + lane, rz);                                    \
                np.f[0] = acc[1][2][0]; np.f[1] = acc[1][2][1];                \
                st_u64_coh(t1p + 64 + lane, np.u);                             \
            }                                                                  \
            if ((T) >= TT - 8) { WAITV0(); } else { WAITV(36); }               \
            ENDBAR();                                                          \
        }
        for (int tb = 0; tb < TT; tb += 4) {
            M1_BODY(tb+0, 0) M1_BODY(tb+1, 1) M1_BODY(tb+2, 2) M1_BODY(tb+3, 3)
        }
#undef M1_BODY
        WAITV0();
        __syncthreads();
        if (tid == 0) post_prog(&prog[P_M1], 1000000);

    } else if (stage == 1) {
        // ================= A: layer-1 recurrence =================
        bf16x8 Wh[2][3][8]; float bnn[2];
        #pragma unroll
        for (int b2 = 0; b2 < 2; ++b2) {
            const int colg = (wave*2 + b2)*16 + ln;
            #pragma unroll
            for (int g = 0; g < 3; ++g)
                #pragma unroll
                for (int kc = 0; kc < 8; ++kc)
                    Wh[b2][g][kc] = ldfrag_f32(whh1 + (g*256 + colg)*HH + kc*32 + qd*8);
            bnn[b2] = bhh1[512 + colg];
        }
        float hold[2][2] = {{0.f,0.f},{0.f,0.f}};
        u64 prz0[2], pn0[2], prz1[2], pn1[2], prz2[2], pn2[2], prz3[2], pn3[2];

        poll_ge(&prog[P_M1], 3);
#define A_PRO(S) { char* slot = ws + OFF_GI1 + ((size_t)cl*RD + (S))*GI_SLOT;  \
        const u64* t0p = (const u64*)(slot + tile0*1024);                      \
        const u64* t1p = (const u64*)(slot + tile1*1024);                      \
        prz##S[0] = ld_u64_coh(t0p + lane); pn##S[0] = ld_u64_coh(t0p + 64 + lane); \
        prz##S[1] = ld_u64_coh(t1p + lane); pn##S[1] = ld_u64_coh(t1p + 64 + lane); }
        A_PRO(0) A_PRO(1) A_PRO(2) A_PRO(3)
#undef A_PRO
        WAITV0();

#define A_BODY(T, S)                                                           \
        {                                                                      \
            if (tid == 0 && (T) >= 5) post_prog(&prog[P_A], (T) - 5);          \
            if (((T) & 7) == 0) poll2_ge(&prog[P_M1], (T) + 12, &prog[P_M2], (T) - 24); \
            CFENCE();                                                          \
            f32x4 aR[2], aZ[2], aN[2]; float gn[2][2];                         \
            {                                                                  \
                unsigned rzl = (unsigned)prz##S[0], rzh = (unsigned)(prz##S[0] >> 32); \
                aR[0] = f32x4{bf2f_lo(rzl), bf2f_hi(rzl), 0.f, 0.f};           \
                aZ[0] = f32x4{bf2f_lo(rzh), bf2f_hi(rzh), 0.f, 0.f};           \
                rzl = (unsigned)prz##S[1]; rzh = (unsigned)(prz##S[1] >> 32);  \
                aR[1] = f32x4{bf2f_lo(rzl), bf2f_hi(rzl), 0.f, 0.f};           \
                aZ[1] = f32x4{bf2f_lo(rzh), bf2f_hi(rzh), 0.f, 0.f};           \
                union { u64 u; float f[2]; } c;                                \
                c.u = pn##S[0]; gn[0][0] = c.f[0]; gn[0][1] = c.f[1];          \
                c.u = pn##S[1]; gn[1][0] = c.f[0]; gn[1][1] = c.f[1];          \
                aN[0] = f32x4{bnn[0], bnn[0], 0.f, 0.f};                       \
                aN[1] = f32x4{bnn[1], bnn[1], 0.f, 0.f};                       \
            }                                                                  \
            if ((T) + 4 < TT) {                                                \
                char* slot = ws + OFF_GI1 + ((size_t)cl*RD + (((T)+4) & (RD-1)))*GI_SLOT; \
                const u64* t0p = (const u64*)(slot + tile0*1024);              \
                const u64* t1p = (const u64*)(slot + tile1*1024);              \
                prz##S[0] = ld_u64_coh(t0p + lane); pn##S[0] = ld_u64_coh(t0p + 64 + lane); \
                prz##S[1] = ld_u64_coh(t1p + lane); pn##S[1] = ld_u64_coh(t1p + 64 + lane); \
            }                                                                  \
            CFENCE();                                                          \
            const int rb = ((T) + 1) & 1, wb = (T) & 1;                        \
            _Pragma("unroll")                                                  \
            for (int kc = 0; kc < 8; ++kc) {                                   \
                bf16x8 f = *(const bf16x8*)&hb[rb][ln][kc*32 + qd*8];          \
                aR[0] = __builtin_amdgcn_mfma_f32_16x16x32_bf16(f, Wh[0][0][kc], aR[0], 0,0,0); \
                aR[1] = __builtin_amdgcn_mfma_f32_16x16x32_bf16(f, Wh[1][0][kc], aR[1], 0,0,0); \
                aZ[0] = __builtin_amdgcn_mfma_f32_16x16x32_bf16(f, Wh[0][1][kc], aZ[0], 0,0,0); \
                aZ[1] = __builtin_amdgcn_mfma_f32_16x16x32_bf16(f, Wh[1][1][kc], aZ[1], 0,0,0); \
                aN[0] = __builtin_amdgcn_mfma_f32_16x16x32_bf16(f, Wh[0][2][kc], aN[0], 0,0,0); \
                aN[1] = __builtin_amdgcn_mfma_f32_16x16x32_bf16(f, Wh[1][2][kc], aN[1], 0,0,0); \
            }                                                                  \
            CFENCE();                                                          \
            unsigned* h1slot = (unsigned*)(ws + OFF_H1R + ((size_t)cl*RD + ((T) & (RD-1)))*4096u); \
            _Pragma("unroll")                                                  \
            for (int b2 = 0; b2 < 2; ++b2) {                                   \
                const int colg = (wave*2 + b2)*16 + ln;                        \
                unsigned pk = 0;                                               \
                _Pragma("unroll")                                              \
                for (int r = 0; r < 2; ++r) {                                  \
                    float rg = sigm_f(aR[b2][r]);                              \
                    float zg = sigm_f(aZ[b2][r]);                              \
                    float ng = tanh_f(gn[b2][r] + rg * aN[b2][r]);             \
                    float h  = (1.f - zg)*ng + zg*hold[b2][r];                 \
                    hold[b2][r] = h;                                           \
                    short hs = f2bf(h);                                        \
                    hb[wb][qd*4 + r][colg] = hs;                               \
                    pk |= (unsigned)(unsigned short)hs << (16*r);              \
                }                                                              \
                st_u32_coh(h1slot + colg*4 + qd, pk);                          \
            }                                                                  \
            if ((T) >= TT - 8) { WAITV0(); } else { WAITV(18); }               \
            WAITL0();                                                          \
            ENDBAR();                                                          \
        }
        for (int tb = 0; tb < TT; tb += 4) {
            A_BODY(tb+0, 0) A_BODY(tb+1, 1) A_BODY(tb+2, 2) A_BODY(tb+3, 3)
        }
#undef A_BODY
        WAITV0();
        __syncthreads();
        if (tid == 0) post_prog(&prog[P_A], 1000000);

    } else if (stage == 2) {
        // ================= M2: gi2 = h1 @ Wih2^T =================
        bf16x8 Wi[2][3][8]; float c0s[2][3];
        #pragma unroll
        for (int b2 = 0; b2 < 2; ++b2)
        #pragma unroll
        for (int g = 0; g < 3; ++g) {
            const int grow = g*256 + (wave*2 + b2)*16 + ln;
            #pragma unroll
            for (int kc = 0; kc < 8; ++kc)
                Wi[b2][g][kc] = ldfrag_f32(wih2 + grow*HH + kc*32 + qd*8);
            c0s[b2][g] = bih2[grow] + (g < 2 ? bhh2[grow] : 0.f);
        }
        const int base = (tid & 1) * 8, pcol = tid >> 1;
        u64 vc0, vc1, vc2, vc3;

        // prologue: h1(0) -> hb[0]; sets hold h1(1..4): set k%4 for h1(k)
        poll_ge(&prog[P_A], 4);
        {
            const u64* h1s = (const u64*)(ws + OFF_H1R + (size_t)cl*RD*4096u);
            u64 v = ld_u64_coh(h1s + tid);
            WAITV0();
            unsigned lo = (unsigned)v, hi = (unsigned)(v >> 32);
            hb[0][base + 0][pcol] = (short)lo;
            hb[0][base + 1][pcol] = (short)(lo >> 16);
            hb[0][base + 4][pcol] = (short)hi;
            hb[0][base + 5][pcol] = (short)(hi >> 16);
        }
        vc1 = ld_u64_coh((const u64*)(ws + OFF_H1R + ((size_t)cl*RD + 1)*4096u) + tid);
        vc2 = ld_u64_coh((const u64*)(ws + OFF_H1R + ((size_t)cl*RD + 2)*4096u) + tid);
        vc3 = ld_u64_coh((const u64*)(ws + OFF_H1R + ((size_t)cl*RD + 3)*4096u) + tid);
        vc0 = ld_u64_coh((const u64*)(ws + OFF_H1R + ((size_t)cl*RD + 4)*4096u) + tid);
        WAITV0();
        __syncthreads();

#define M2_BODY(U, SN)  /* SN = (U+1)&3: the set holding h1(U+1) */            \
        {                                                                      \
            if (tid == 0 && (U) >= 5) post_prog(&prog[P_M2], (U) - 5);         \
            if (((U) & 7) == 0) poll2_ge(&prog[P_A], (U) + 12, &prog[P_B], (U) - 24); \
            CFENCE();                                                          \
            if ((U) + 1 < TT) {   /* unpack h1(U+1), loaded 4 iters ago */     \
                unsigned lo = (unsigned)vc##SN, hi = (unsigned)(vc##SN >> 32); \
                hb[((U)+1) & 1][base + 0][pcol] = (short)lo;                   \
                hb[((U)+1) & 1][base + 1][pcol] = (short)(lo >> 16);           \
                hb[((U)+1) & 1][base + 4][pcol] = (short)hi;                   \
                hb[((U)+1) & 1][base + 5][pcol] = (short)(hi >> 16);           \
            }                                                                  \
            if ((U) + 5 < TT)                                                  \
                vc##SN = ld_u64_coh((const u64*)(ws + OFF_H1R + ((size_t)cl*RD + (((U)+5) & (RD-1)))*4096u) + tid); \
            CFENCE();                                                          \
            f32x4 acc[2][3];                                                   \
            _Pragma("unroll")                                                  \
            for (int b2 = 0; b2 < 2; ++b2)                                     \
            _Pragma("unroll")                                                  \
            for (int g = 0; g < 3; ++g) {                                      \
                float c0 = c0s[b2][g];                                         \
                acc[b2][g] = f32x4{c0, c0, c0, c0};                            \
            }                                                                  \
            _Pragma("unroll")                                                  \
            for (int kc = 0; kc < 8; ++kc) {                                   \
                bf16x8 f = *(const bf16x8*)&hb[(U) & 1][ln][kc*32 + qd*8];     \
                _Pragma("unroll")                                              \
                for (int b2 = 0; b2 < 2; ++b2)                                 \
                _Pragma("unroll")                                              \
                for (int g = 0; g < 3; ++g)                                    \
                    acc[b2][g] = __builtin_amdgcn_mfma_f32_16x16x32_bf16(f, Wi[b2][g][kc], acc[b2][g], 0, 0, 0); \
            }                                                                  \
            CFENCE();                                                          \
            char* slot = ws + OFF_GI2 + ((size_t)cl*RD + ((U) & (RD-1)))*GI_SLOT; \
            {                                                                  \
                u64* t0p = (u64*)(slot + tile0*1024);                          \
                u64 rz = (u64)pk2bf(acc[0][0][0], acc[0][0][1])                \
                       | ((u64)pk2bf(acc[0][1][0], acc[0][1][1]) << 32);       \
                st_u64_coh(t0p + lane, rz);                                    \
                union { float f[2]; u64 u; } np;                               \
                np.f[0] = acc[0][2][0]; np.f[1] = acc[0][2][1];                \
                st_u64_coh(t0p + 64 + lane, np.u);                             \
                u64* t1p = (u64*)(slot + tile1*1024);                          \
                rz = (u64)pk2bf(acc[1][0][0], acc[1][0][1])                    \
                   | ((u64)pk2bf(acc[1][1][0], acc[1][1][1]) << 32);           \
                st_u64_coh(t1p + lane, rz);                                    \
                np.f[0] = acc[1][2][0]; np.f[1] = acc[1][2][1];                \
                st_u64_coh(t1p + 64 + lane, np.u);                             \
            }                                                                  \
            if ((U) >= TT - 8) { WAITV0(); } else { WAITV(15); }               \
            WAITL0();                                                          \
            ENDBAR();                                                          \
        }
        for (int ub = 0; ub < TT; ub += 4) {
            M2_BODY(ub+0, 1) M2_BODY(ub+1, 2) M2_BODY(ub+2, 3) M2_BODY(ub+3, 0)
        }
#undef M2_BODY
        WAITV0();
        __syncthreads();
        if (tid == 0) post_prog(&prog[P_M2], 1000000);

    } else {
        // ================= B: layer-2 recurrence + h2seq + BN =================
        bf16x8 Wh[2][3][8]; float bnn[2];
        #pragma unroll
        for (int b2 = 0; b2 < 2; ++b2) {
            const int colg = (wave*2 + b2)*16 + ln;
            #pragma unroll
            for (int g = 0; g < 3; ++g)
                #pragma unroll
                for (int kc = 0; kc < 8; ++kc)
                    Wh[b2][g][kc] = ldfrag_f32(whh2 + (g*256 + colg)*HH + kc*32 + qd*8);
            bnn[b2] = bhh2[512 + colg];
        }
        float* bnsum = (float*)(ws + OFF_BNSUM);
        float* bnsq  = (float*)(ws + OFF_BNSQ);
        float hold[2][2] = {{0.f,0.f},{0.f,0.f}};
        float cbs[2] = {0.f, 0.f}, cbq[2] = {0.f, 0.f};
        u64 prz0[2], pn0[2], prz1[2], pn1[2], prz2[2], pn2[2], prz3[2], pn3[2];

        poll_ge(&prog[P_M2], 3);
#define B_PRO(S) { char* slot = ws + OFF_GI2 + ((size_t)cl*RD + (S))*GI_SLOT;  \
        const u64* t0p = (const u64*)(slot + tile0*1024);                      \
        const u64* t1p = (const u64*)(slot + tile1*1024);                      \
        prz##S[0] = ld_u64_coh(t0p + lane); pn##S[0] = ld_u64_coh(t0p + 64 + lane); \
        prz##S[1] = ld_u64_coh(t1p + lane); pn##S[1] = ld_u64_coh(t1p + 64 + lane); }
        B_PRO(0) B_PRO(1) B_PRO(2) B_PRO(3)
#undef B_PRO
        WAITV0();
        __syncthreads();

#define B_BODY(V, S)                                                           \
        {                                                                      \
            if (tid == 0 && (V) >= 5) post_prog(&prog[P_B], (V) - 5);          \
            if (((V) & 7) == 0) poll_ge(&prog[P_M2], (V) + 12);                \
            CFENCE();                                                          \
            f32x4 aR[2], aZ[2], aN[2]; float gn[2][2];                         \
            {                                                                  \
                unsigned rzl = (unsigned)prz##S[0], rzh = (unsigned)(prz##S[0] >> 32); \
                aR[0] = f32x4{bf2f_lo(rzl), bf2f_hi(rzl), 0.f, 0.f};           \
                aZ[0] = f32x4{bf2f_lo(rzh), bf2f_hi(rzh), 0.f, 0.f};           \
                rzl = (unsigned)prz##S[1]; rzh = (unsigned)(prz##S[1] >> 32);  \
                aR[1] = f32x4{bf2f_lo(rzl), bf2f_hi(rzl), 0.f, 0.f};           \
                aZ[1] = f32x4{bf2f_lo(rzh), bf2f_hi(rzh), 0.f, 0.f};           \
                union { u64 u; float f[2]; } c;                                \
                c.u = pn##S[0]; gn[0][0] = c.f[0]; gn[0][1] = c.f[1];          \
                c.u = pn##S[1]; gn[1][0] = c.f[0]; gn[1][1] = c.f[1];          \
                aN[0] = f32x4{bnn[0], bnn[0], 0.f, 0.f};                       \
                aN[1] = f32x4{bnn[1], bnn[1], 0.f, 0.f};                       \
            }                                                                  \
            if ((V) + 4 < TT) {                                                \
                char* slot = ws + OFF_GI2 + ((size_t)cl*RD + (((V)+4) & (RD-1)))*GI_SLOT; \
                const u64* t0p = (const u64*)(slot + tile0*1024);              \
                const u64* t1p = (const u64*)(slot + tile1*1024);              \
                prz##S[0] = ld_u64_coh(t0p + lane); pn##S[0] = ld_u64_coh(t0p + 64 + lane); \
                prz##S[1] = ld_u64_coh(t1p + lane); pn##S[1] = ld_u64_coh(t1p + 64 + lane); \
            }                                                                  \
            CFENCE();                                                          \
            const int rb = ((V) + 1) & 1, wb = (V) & 1;                        \
            _Pragma("unroll")                                                  \
            for (int kc = 0; kc < 8; ++kc) {                                   \
                bf16x8 f = *(const bf16x8*)&hb[rb][ln][kc*32 + qd*8];          \
                aR[0] = __builtin_amdgcn_mfma_f32_16x16x32_bf16(f, Wh[0][0][kc], aR[0], 0,0,0); \
                aR[1] = __builtin_amdgcn_mfma_f32_16x16x32_bf16(f, Wh[1][0][kc], aR[1], 0,0,0); \
                aZ[0] = __builtin_amdgcn_mfma_f32_16x16x32_bf16(f, Wh[0][1][kc], aZ[0], 0,0,0); \
                aZ[1] = __builtin_amdgcn_mfma_f32_16x16x32_bf16(f, Wh[1][1][kc], aZ[1], 0,0,0); \
                aN[0] = __builtin_amdgcn_mfma_f32_16x16x32_bf16(f, Wh[0][2][kc], aN[0], 0,0,0); \
                aN[1] = __builtin_amdgcn_mfma_f32_16x16x32_bf16(f, Wh[1][2][kc], aN[1], 0,0,0); \
            }                                                                  \
            CFENCE();                                                          \
            _Pragma("unroll")                                                  \
            for (int b2 = 0; b2 < 2; ++b2) {                                   \
                const int colg = (wave*2 + b2)*16 + ln;                        \
                _Pragma("unroll")                                              \
                for (int r = 0; r < 2; ++r) {                                  \
                    float rg = sigm_f(aR[b2][r]);                              \
                    float zg = sigm_f(aZ[b2][r]);                              \
                    float ng = tanh_f(gn[b2][r] + rg * aN[b2][r]);             \
                    float h  = (1.f - zg)*ng + zg*hold[b2][r];                 \
                    hold[b2][r] = h;                                           \
                    cbs[b2] += h; cbq[b2] += h*h;                              \
                    short hs = f2bf(h);                                        \
                    hb[wb][qd*4 + r][colg] = hs;                               \
                    h2seq[((size_t)(V)*BB + grow0 + qd*2 + r)*HH + colg] = hs; \
                }                                                              \
            }                                                                  \
            if ((V) >= TT - 8) { WAITV0(); } else { WAITV(24); }               \
            WAITL0();                                                          \
            ENDBAR();                                                          \
        }
        for (int vb = 0; vb < TT; vb += 4) {
            B_BODY(vb+0, 0) B_BODY(vb+1, 1) B_BODY(vb+2, 2) B_BODY(vb+3, 3)
        }
#undef B_BODY
        #pragma unroll
        for (int b2 = 0; b2 < 2; ++b2) {
            const int colg = (wave*2 + b2)*16 + ln;
            atomicAdd(&bnsum[colg], cbs[b2]);
            atomicAdd(&bnsq[colg],  cbq[b2]);
        }
        WAITV0();
        __syncthreads();
        if (tid == 0) post_prog(&prog[P_B], 1000000);
    }
}

// ---------------- BN finalize + hardtanh + temporal mean + FC ----------------
__global__ void gru_final(const char* __restrict__ ws,
                          const float* __restrict__ gamma, const float* __restrict__ beta,
                          const float* __restrict__ fcw, const float* __restrict__ fcb,
                          float* __restrict__ out)
{
    __shared__ float summ[HH];
    const int b = blockIdx.x, c = threadIdx.x;
    const float* bnsum = (const float*)(ws + OFF_BNSUM);
    const float* bnsq  = (const float*)(ws + OFF_BNSQ);
    const short* h2seq = (const short*)(ws + OFF_H2SEQ);

    const float inv = 1.f / (float)(BB * TT);
    float mean = bnsum[c] * inv;
    float var  = bnsq[c] * inv - mean * mean;
    float scale = rsqrtf(var + EPSV) * gamma[c];
    float shift = beta[c] - mean * scale;

    const short* p = h2seq + (size_t)b*HH + c;    // [t][b][h]
    float acc = 0.f;
    #pragma unroll 4
    for (int t = 0; t < TT; ++t) {
        float v = bf2f(p[(size_t)t*BB*HH]) * scale + shift;
        v = fminf(fmaxf(v, -2.f), 2.f);
        acc += v;
    }
    summ[c] = acc * (1.f / TT);
    __syncthreads();
    if (c < OUTD) {
        float d = fcb[c];
        const float* wr = fcw + c*HH;
        #pragma unroll 8
        for (int h = 0; h < HH; ++h) d += wr[h] * summ[h];
        out[b*OUTD + c] = d;
    }
}

extern "C" void kernel_launch(void* const* d_in, const int* in_sizes, int n_in,
                              void* d_out, int out_size, void* d_ws, size_t ws_size,
                              hipStream_t stream)
{
    const float* x    = (const float*)d_in[0];
    const float* wih1 = (const float*)d_in[1];
    const float* whh1 = (const float*)d_in[2];
    const float* bih1 = (const float*)d_in[3];
    const float* bhh1 = (const float*)d_in[4];
    const float* wih2 = (const float*)d_in[5];
    const float* whh2 = (const float*)d_in[6];
    const float* bih2 = (const float*)d_in[7];
    const float* bhh2 = (const float*)d_in[8];
    const float* gamma= (const float*)d_in[9];
    const float* beta = (const float*)d_in[10];
    const float* fcw  = (const float*)d_in[11];
    const float* fcb  = (const float*)d_in[12];
    char* ws = (char*)d_ws;

    // progress counters + BN accumulators start at 0 (re-zeroed every replay)
    (void)hipMemsetAsync(ws, 0, OFF_ZERO_END, stream);

    // 32 clusters x 4 stages = 128 co-resident WGs (one per CU)
    hipLaunchKernelGGL(gru_pipe, dim3(NCL*4), dim3(512), 0, stream,
                       x, wih1, whh1, bih1, bhh1, wih2, whh2, bih2, bhh2, ws);

    hipLaunchKernelGGL(gru_final, dim3(BB), dim3(HH), 0, stream,
                       (const char*)ws, gamma, beta, fcw, fcb, (float*)d_out);
}